// Round 1
// baseline (175.679 us; speedup 1.0000x reference)
//
#include <hip/hip_runtime.h>
#include <cstdint>

// ---------------------------------------------------------------------------
// CTC loss pipeline:
//   k_prep : x fp32->bf16, W[D,V] -> Wt[V,D] bf16, zero d_out
//   k_gemm : m97-structure bf16 MFMA GEMM, BK=64, 1-D grid with chunked-XCD
//            swizzle (n-major) so the 8 N-tiles sharing an A-panel share an L2
//   k_softmax_gather : row lse + ext-label exp-gather -> pext rows of 256
//            floats (s=0..255) + compact p4[row] sidecar (s=256)
//   k_ctc  : scaled linear-domain CTC forward, single wave per batch,
//            async global_load_lds ring (8 slots x 8 rows x 1KiB), depth 6
//            chunks (48 loads in flight), counted s_waitcnt vmcnt(48).
// ---------------------------------------------------------------------------

#define PROW 256                      // pext row: exactly 1 KiB (one gload_lds row)
#define PEXT_PAD_ROWS 64              // prefetch overrun pad (loaded, never consumed)
#define CTC_D 6                       // prefetch depth in chunks (6*8=48 vmem in flight)
#define CTC_NS 8                      // LDS ring slots (power of 2, > CTC_D)
#define L2E 1.4426950408889634f
#define LN2 0.6931471805599453f

typedef short v8s __attribute__((ext_vector_type(8)));
typedef float v4f __attribute__((ext_vector_type(4)));

__device__ __forceinline__ uint32_t f2bf_bits(float f) {
  uint32_t u = __float_as_uint(f);
  return (u + 0x7FFFu + ((u >> 16) & 1u)) >> 16;   // RNE
}
__device__ __forceinline__ float bf2f(uint32_t h) { return __uint_as_float(h << 16); }

// ---------------- k_prep: x fp32->bf16, W transpose->bf16, zero d_out ----------------
__global__ void k_prep(const float* __restrict__ x, uint16_t* __restrict__ xb, long long n,
                       const float* __restrict__ W, uint16_t* __restrict__ Wt, int D, int V,
                       float* __restrict__ out, int nconv) {
  if (blockIdx.x == 0 && threadIdx.x == 0) out[0] = 0.f;   // zero the atomic target
  if ((int)blockIdx.x < nconv) {
    long long i = ((long long)blockIdx.x * blockDim.x + threadIdx.x) * 8;
    if (i >= n) return;
    float4 a = *(const float4*)(x + i);
    float4 b = *(const float4*)(x + i + 4);
    uint4 o;
    o.x = f2bf_bits(a.x) | (f2bf_bits(a.y) << 16);
    o.y = f2bf_bits(a.z) | (f2bf_bits(a.w) << 16);
    o.z = f2bf_bits(b.x) | (f2bf_bits(b.y) << 16);
    o.w = f2bf_bits(b.z) | (f2bf_bits(b.w) << 16);
    *(uint4*)(xb + i) = o;
  } else {
    __shared__ float tile[32][33];
    const int bid2 = blockIdx.x - nconv;
    const int n0 = (bid2 % (V / 32)) * 32, k0 = (bid2 / (V / 32)) * 32;
    const int tx = threadIdx.x & 31, ty = threadIdx.x >> 5;   // (32,8)
    #pragma unroll
    for (int i = 0; i < 32; i += 8)
      tile[ty + i][tx] = W[(size_t)(k0 + ty + i) * V + n0 + tx];
    __syncthreads();
    #pragma unroll
    for (int i = 0; i < 32; i += 8)
      Wt[(size_t)(n0 + ty + i) * D + k0 + tx] = (uint16_t)f2bf_bits(tile[tx][ty + i]);
  }
}

// ---------------- k_gemm: m97 structure, BK=64, bf16 out, 1-D swizzled grid ----------------
// A:[M,K] bf16, Bt:[N,K] bf16 (=W^T). 128x128 tile, 4 waves, 2 K-halves per
// barrier pair (32 MFMA/barrier). LDS 32 KB.
__global__ __launch_bounds__(256) void k_gemm(const uint16_t* __restrict__ A,
                                              const uint16_t* __restrict__ Bt,
                                              const float* __restrict__ bias,
                                              uint16_t* __restrict__ C, int M, int N, int K) {
  __shared__ uint16_t As[2][128 * 32];   // [k-half][row*32 + k]  (64B rows)
  __shared__ uint16_t Bs[2][128 * 32];
  const int tid = threadIdx.x, lane = tid & 63, wave = tid >> 6;
  // chunked-XCD swizzle: XCD (d&7) owns a contiguous wg range => the N/128
  // blocks sharing one A-panel are co-resident on one XCD's L2 (3MB < 4MB).
  int d = blockIdx.x;
  const int nwg = gridDim.x;
  if ((nwg & 7) == 0) d = (d & 7) * (nwg >> 3) + (d >> 3);
  const int ntl = N >> 7;                       // N-tiles (n-major: fastest)
  const int m0 = (d / ntl) * 128, n0 = (d % ntl) * 128;
  const int wm = wave & 1, wn = wave >> 1;
  const int frow = lane & 15, kb = lane >> 4;
  const int lr = lane >> 2, kc = lane & 3;
  v4f acc[4][4] = {};

  for (int k0 = 0; k0 < K; k0 += 64) {
    __syncthreads();
    #pragma unroll
    for (int t = 0; t < 2; t++)
      #pragma unroll
      for (int i = 0; i < 2; i++) {
        const int r = (wave * 2 + i) * 16 + lr;
        const uint16_t* ga = A + (size_t)(m0 + r) * K + k0 + t * 32 + kc * 8;
        const uint16_t* gb = Bt + (size_t)(n0 + r) * K + k0 + t * 32 + kc * 8;
        __builtin_amdgcn_global_load_lds(
            (const __attribute__((address_space(1))) void*)ga,
            (__attribute__((address_space(3))) void*)(&As[t][0] + (wave * 2 + i) * 512 + lane * 8), 16, 0, 0);
        __builtin_amdgcn_global_load_lds(
            (const __attribute__((address_space(1))) void*)gb,
            (__attribute__((address_space(3))) void*)(&Bs[t][0] + (wave * 2 + i) * 512 + lane * 8), 16, 0, 0);
      }
    __syncthreads();

    #pragma unroll
    for (int t = 0; t < 2; t++) {
      v8s af[4], bf[4];
      #pragma unroll
      for (int i = 0; i < 4; i++)
        af[i] = *(const v8s*)(&As[t][0] + (wm * 64 + i * 16 + frow) * 32 + kb * 8);
      #pragma unroll
      for (int j = 0; j < 4; j++)
        bf[j] = *(const v8s*)(&Bs[t][0] + (wn * 64 + j * 16 + frow) * 32 + kb * 8);
      #pragma unroll
      for (int i = 0; i < 4; i++)
        #pragma unroll
        for (int j = 0; j < 4; j++)
          acc[i][j] = __builtin_amdgcn_mfma_f32_16x16x32_bf16(af[i], bf[j], acc[i][j], 0, 0, 0);
    }
  }

  // epilogue: C/D layout col=lane&15, row=(lane>>4)*4+reg  [m89-verified]
  const int crow = (lane >> 4) * 4, ccol = lane & 15;
  #pragma unroll
  for (int j = 0; j < 4; j++) {
    const int n = n0 + wn * 64 + j * 16 + ccol;
    const float bv = bias[n];
    #pragma unroll
    for (int i = 0; i < 4; i++) {
      const int mb = m0 + wm * 64 + i * 16 + crow;
      #pragma unroll
      for (int r2 = 0; r2 < 4; r2++)
        C[(size_t)(mb + r2) * N + n] = (uint16_t)f2bf_bits(acc[i][j][r2] + bv);
    }
  }
}

// ---------------- k_softmax_gather: row lse + gather (linear domain) ----------------
__global__ void k_softmax_gather(const uint16_t* __restrict__ logits, const int* __restrict__ target,
                                 const int* __restrict__ tlen, float* __restrict__ pext,
                                 float* __restrict__ p4arr, int T, int V, int L) {
  const int row = blockIdx.x * 4 + (threadIdx.x >> 6);   // one wave per row
  const int lane = threadIdx.x & 63;
  const uint16_t* lrow = logits + (size_t)row * V;

  float xs[16];
  int cnt = 0;
  float mx = -INFINITY;
  for (int base = 0; base < V; base += 256) {
    const int idx = base + lane * 4;
    uint2 u = *(const uint2*)(lrow + idx);
    float4 v;
    v.x = bf2f(u.x & 0xFFFFu); v.y = bf2f(u.x >> 16);
    v.z = bf2f(u.y & 0xFFFFu); v.w = bf2f(u.y >> 16);
    xs[cnt] = v.x; xs[cnt + 1] = v.y; xs[cnt + 2] = v.z; xs[cnt + 3] = v.w; cnt += 4;
    mx = fmaxf(mx, fmaxf(fmaxf(v.x, v.y), fmaxf(v.z, v.w)));
  }
  #pragma unroll
  for (int off = 32; off; off >>= 1) mx = fmaxf(mx, __shfl_xor(mx, off, 64));
  float sum = 0.f;
  #pragma unroll
  for (int q = 0; q < 16; q++) { if (q < cnt) sum += exp2f((xs[q] - mx) * L2E); }
  #pragma unroll
  for (int off = 32; off; off >>= 1) sum += __shfl_xor(sum, off, 64);
  const float lse2 = mx * L2E + log2f(sum);

  const int bidx = row / T;
  const int Lb = tlen[bidx];
  const int S = 2 * Lb + 1;
  float* prow = pext + (size_t)row * PROW;
  #pragma unroll
  for (int it = 0; it < PROW / 64; it++) {
    const int s = lane + it * 64;
    float p = 0.f;
    if (s < S) {
      const int lbl = (s & 1) ? target[bidx * L + ((s - 1) >> 1)] : 0;
      p = exp2f(bf2f(lrow[lbl]) * L2E - lse2);
    }
    prow[s] = p;
  }
  if (lane == 0) {    // s=256 sidecar (even state -> blank label)
    float p = 0.f;
    if (256 < S) p = exp2f(bf2f(lrow[0]) * L2E - lse2);
    p4arr[row] = p;
  }
}

// ---------------- k_ctc: scaled linear-domain CTC forward, 1 wave per batch ----------------
__device__ __forceinline__ float wave_shr1(float x) {   // lane l <- lane l-1, lane0 <- 0
  return __int_as_float(__builtin_amdgcn_update_dpp(0, __float_as_int(x), 0x138, 0xf, 0xf, true));
}
__device__ __forceinline__ float wave_max_nonneg(float x) {
  x = fmaxf(x, __int_as_float(__builtin_amdgcn_update_dpp(0, __float_as_int(x), 0x111, 0xf, 0xf, true)));
  x = fmaxf(x, __int_as_float(__builtin_amdgcn_update_dpp(0, __float_as_int(x), 0x112, 0xf, 0xf, true)));
  x = fmaxf(x, __int_as_float(__builtin_amdgcn_update_dpp(0, __float_as_int(x), 0x114, 0xf, 0xf, true)));
  x = fmaxf(x, __int_as_float(__builtin_amdgcn_update_dpp(0, __float_as_int(x), 0x118, 0xf, 0xf, true)));
  x = fmaxf(x, __int_as_float(__builtin_amdgcn_update_dpp(0, __float_as_int(x), 0x142, 0xf, 0xf, true)));
  x = fmaxf(x, __int_as_float(__builtin_amdgcn_update_dpp(0, __float_as_int(x), 0x143, 0xf, 0xf, true)));
  return __int_as_float(__builtin_amdgcn_readlane(__float_as_int(x), 63));
}

__global__ __launch_bounds__(64, 1) void k_ctc(const float* __restrict__ pext,
                                               const float* __restrict__ p4arr,
                                               const int* __restrict__ target,
                                               const int* __restrict__ ilen,
                                               const int* __restrict__ tlen,
                                               float* __restrict__ out, int T, int L) {
  // Single-wave async pipeline: global_load_lds ring, counted vmcnt, no barriers.
  __shared__ __attribute__((aligned(16))) float ring[CTC_NS][8][PROW];  // 64 KiB
  __shared__ float p4l[1024 + 8];                                       // p4 sidecar (t up to 1024)
  __shared__ float abuf[257];

  const int b = blockIdx.x;
  const int lane = threadIdx.x;          // 64 threads = 1 wave
  const int B = gridDim.x;
  const int Tb = ilen[b];
  const int Lb = tlen[b];
  const int S = 2 * Lb + 1;
  const int* tg = target + b * L;

  const int s1 = 4 * lane + 1, s3 = 4 * lane + 3;
  float sk1 = 0.f, sk3 = 0.f;
  if (s1 >= 3 && s1 < S) sk1 = (tg[(s1 - 1) >> 1] != tg[(s1 - 3) >> 1]) ? 1.f : 0.f;
  if (s3 >= 3 && s3 < S) sk3 = (tg[(s3 - 1) >> 1] != tg[(s3 - 3) >> 1]) ? 1.f : 0.f;

  const float* pb = pext + (size_t)b * T * PROW;
  const float* p4b = p4arr + (size_t)b * T;

  // --- init alphas from t=0 row (consumed BEFORE any prefetch is issued, so
  //     the compiler's wait for this load cannot drain the pipeline) ---
  const float4 p0 = *(const float4*)(pb + (lane << 2));
  float a0 = (lane == 0) ? p0.x : 0.f;
  float a1 = (lane == 0) ? p0.y : 0.f;
  float a2 = 0.f, a3 = 0.f, a4 = 0.f;
  float log2C = 0.f;

  // --- stage ALL p4 values up-front (1 gload_lds per 64 rows; oldest in
  //     vmcnt order -> retired before the first counted wait matters) ---
  int ng = (T + 63) >> 6; if (ng > 16) ng = 16;
  for (int g = 0; g < ng; g++)
    __builtin_amdgcn_global_load_lds(
        (const __attribute__((address_space(1))) void*)(p4b + g * 64 + lane),
        (__attribute__((address_space(3))) void*)(&p4l[g * 64]), 4, 0, 0);

  // chunk c covers steps t = 1+8c .. 8+8c  (rows from pext)
  const int CT = (Tb + 6) >> 3;          // ceil((Tb-1)/8)

  #define ISSUE(c) {                                                        \
    const int _slot = (c) & (CTC_NS - 1);                                   \
    const float* _src = pb + (size_t)(1 + 8 * (c)) * PROW + (lane << 2);    \
    _Pragma("unroll")                                                       \
    for (int _k = 0; _k < 8; _k++)                                          \
      __builtin_amdgcn_global_load_lds(                                     \
          (const __attribute__((address_space(1))) void*)(_src + _k * PROW),\
          (__attribute__((address_space(3))) void*)(&ring[_slot][_k][0]), 16, 0, 0); }

  #define CTC_STEP(PP, P4) {                                            \
    const float pm3 = wave_shr1(a3);                                    \
    const float a255 = __int_as_float(__builtin_amdgcn_readlane(__float_as_int(a3), 63)); \
    const float n0v = (a0 + pm3) * (PP).x;                              \
    const float n1v = (a1 + a0 + sk1 * pm3) * (PP).y;                   \
    const float n2v = (a2 + a1) * (PP).z;                               \
    const float n3v = (a3 + a2 + sk3 * a1) * (PP).w;                    \
    const float n4v = (a4 + a255) * (P4);                               \
    a0 = n0v; a1 = n1v; a2 = n2v; a3 = n3v; a4 = n4v; }

  #define RENORM {                                                      \
    float m = fmaxf(fmaxf(fmaxf(a0, a1), fmaxf(a2, a3)), a4);           \
    m = wave_max_nonneg(m);                                             \
    const int e = (int)((__float_as_uint(m) >> 23) & 255u) - 127;       \
    const float scale = __uint_as_float((uint32_t)(127 - e) << 23);     \
    a0 *= scale; a1 *= scale; a2 *= scale; a3 *= scale; a4 *= scale;    \
    log2C += (float)e; }

  // prologue: fill the pipeline CTC_D chunks deep (48 loads in flight)
  const int npre = CT < CTC_D ? CT : CTC_D;
  for (int c = 0; c < npre; c++) ISSUE(c);

  for (int c = 0; c < CT; c++) {
    if (c + CTC_D < CT) {
      ISSUE(c + CTC_D);
      // newest 48 outstanding = chunks c+1..c+CTC_D  =>  chunk c has landed.
      asm volatile("s_waitcnt vmcnt(48)" ::: "memory");
    } else {
      asm volatile("s_waitcnt vmcnt(0)" ::: "memory");   // tail drain (once)
    }
    const int slot = c & (CTC_NS - 1);
    const int t0 = 1 + 8 * c;
    float4 P[8]; float Q[8];
    #pragma unroll
    for (int k = 0; k < 8; k++) {
      P[k] = *(const float4*)(&ring[slot][k][lane << 2]);
      Q[k] = p4l[t0 + k];
    }
    if (t0 + 8 <= Tb) {
      #pragma unroll
      for (int k = 0; k < 8; k++) CTC_STEP(P[k], Q[k]);
      RENORM;
    } else {
      #pragma unroll
      for (int k = 0; k < 8; k++) { if (t0 + k < Tb) CTC_STEP(P[k], Q[k]); }
      RENORM;
    }
  }

  abuf[4 * lane + 0] = a0; abuf[4 * lane + 1] = a1;
  abuf[4 * lane + 2] = a2; abuf[4 * lane + 3] = a3;
  if (lane == 63) abuf[256] = a4;
  __syncthreads();
  if (lane == 0) {
    const float ssum = abuf[2 * Lb - 1] + abuf[2 * Lb];
    const float ll = (log2f(ssum) + log2C) * LN2;
    float nll = -ll;
    if (!(nll < 1e29f)) nll = 0.f;                 // zero_infinity (also catches inf/nan)
    atomicAdd(out, nll / ((float)(Lb > 0 ? Lb : 1) * (float)B));
  }
}

// ---------------------------------------------------------------------------
extern "C" void kernel_launch(void* const* d_in, const int* in_sizes, int n_in,
                              void* d_out, int out_size, void* d_ws, size_t ws_size,
                              hipStream_t stream) {
  const float* x      = (const float*)d_in[0];
  const float* W      = (const float*)d_in[1];
  const float* bias   = (const float*)d_in[2];
  const int*  target  = (const int*)d_in[3];
  const int*  ilen    = (const int*)d_in[4];
  const int*  tlen    = (const int*)d_in[5];

  const int B = in_sizes[4];
  const int V = in_sizes[2];
  const int D = in_sizes[1] / V;
  const int T = in_sizes[0] / (B * D);
  const int L = in_sizes[3] / B;
  const int M = B * T;

  char* ws = (char*)d_ws;
  const size_t xb_bytes = (size_t)M * D * 2;
  const size_t wt_bytes = (size_t)V * D * 2;
  uint16_t* xb = (uint16_t*)ws;
  uint16_t* Wt = (uint16_t*)(ws + xb_bytes);
  uint16_t* logits = (uint16_t*)(ws + xb_bytes + wt_bytes);
  const size_t log_bytes = (size_t)M * V * 2;

  const size_t pext_bytes = (size_t)(M + PEXT_PAD_ROWS) * PROW * 4;
  const size_t p4_bytes = (size_t)(M + PEXT_PAD_ROWS) * 4;
  float* pext; float* p4a;
  if (pext_bytes + p4_bytes <= xb_bytes + wt_bytes) {
    pext = (float*)ws;                 // overlay dead xb/Wt region after GEMM
    p4a  = (float*)(ws + pext_bytes);
  } else {
    pext = (float*)(ws + xb_bytes + wt_bytes + log_bytes);
    p4a  = (float*)(ws + xb_bytes + wt_bytes + log_bytes + pext_bytes);
  }

  const long long nx = (long long)M * D;
  const int nconv = (int)((nx / 8 + 255) / 256);
  const int ntrans = (V / 32) * (D / 32);
  k_prep<<<nconv + ntrans, 256, 0, stream>>>(x, xb, nx, W, Wt, D, V, (float*)d_out, nconv);
  k_gemm<<<(M / 128) * (V / 128), 256, 0, stream>>>(xb, Wt, bias, logits, M, V, D);
  k_softmax_gather<<<M / 4, 256, 0, stream>>>(logits, target, tlen, pext, p4a, T, V, L);
  k_ctc<<<B, 64, 0, stream>>>(pext, p4a, target, ilen, tlen, (float*)d_out, T, L);
}

// Round 4
// 160.172 us; speedup vs baseline: 1.0968x; 1.0968x over previous
//
#include <hip/hip_runtime.h>
#include <cstdint>

// ---------------------------------------------------------------------------
// CTC loss pipeline:
//   k_prep : x fp32->bf16, W[D,V] -> Wt[V,D] bf16, zero d_out
//   k_gemm : m97-structure bf16 MFMA GEMM, BK=64, 1-D grid with chunked-XCD
//            swizzle (n-major)
//   k_softmax_gather : row lse + ext-label exp-gather -> pext rows of 256
//            floats (s=0..255). State 256 (blank) == prow[0], no sidecar.
//   k_ctc  : scaled linear-domain CTC forward, single wave per batch,
//            4-deep register pipeline, 8 VMEM ops per 8-row chunk (minimum),
//            p4 (state 256) recovered via readlane(P.x, 0) -- zero extra loads.
// ---------------------------------------------------------------------------

#define PROW 256                      // pext row: 256 floats = 1 KiB
#define PEXT_PAD_ROWS 64              // prefetch overrun pad (loaded, never consumed)
#define L2E 1.4426950408889634f
#define LN2 0.6931471805599453f

typedef short v8s __attribute__((ext_vector_type(8)));
typedef float v4f __attribute__((ext_vector_type(4)));

__device__ __forceinline__ uint32_t f2bf_bits(float f) {
  uint32_t u = __float_as_uint(f);
  return (u + 0x7FFFu + ((u >> 16) & 1u)) >> 16;   // RNE
}
__device__ __forceinline__ float bf2f(uint32_t h) { return __uint_as_float(h << 16); }

// ---------------- k_prep: x fp32->bf16, W transpose->bf16, zero d_out ----------------
__global__ void k_prep(const float* __restrict__ x, uint16_t* __restrict__ xb, long long n,
                       const float* __restrict__ W, uint16_t* __restrict__ Wt, int D, int V,
                       float* __restrict__ out, int nconv) {
  if (blockIdx.x == 0 && threadIdx.x == 0) out[0] = 0.f;   // zero the atomic target
  if ((int)blockIdx.x < nconv) {
    long long i = ((long long)blockIdx.x * blockDim.x + threadIdx.x) * 8;
    if (i >= n) return;
    float4 a = *(const float4*)(x + i);
    float4 b = *(const float4*)(x + i + 4);
    uint4 o;
    o.x = f2bf_bits(a.x) | (f2bf_bits(a.y) << 16);
    o.y = f2bf_bits(a.z) | (f2bf_bits(a.w) << 16);
    o.z = f2bf_bits(b.x) | (f2bf_bits(b.y) << 16);
    o.w = f2bf_bits(b.z) | (f2bf_bits(b.w) << 16);
    *(uint4*)(xb + i) = o;
  } else {
    __shared__ float tile[32][33];
    const int bid2 = blockIdx.x - nconv;
    const int n0 = (bid2 % (V / 32)) * 32, k0 = (bid2 / (V / 32)) * 32;
    const int tx = threadIdx.x & 31, ty = threadIdx.x >> 5;   // (32,8)
    #pragma unroll
    for (int i = 0; i < 32; i += 8)
      tile[ty + i][tx] = W[(size_t)(k0 + ty + i) * V + n0 + tx];
    __syncthreads();
    #pragma unroll
    for (int i = 0; i < 32; i += 8)
      Wt[(size_t)(n0 + ty + i) * D + k0 + tx] = (uint16_t)f2bf_bits(tile[tx][ty + i]);
  }
}

// ---------------- k_gemm: m97 structure, BK=64, bf16 out, 1-D swizzled grid ----------------
// A:[M,K] bf16, Bt:[N,K] bf16 (=W^T). 128x128 tile, 4 waves, 2 K-halves per
// barrier pair (32 MFMA/barrier). LDS 32 KB.
__global__ __launch_bounds__(256) void k_gemm(const uint16_t* __restrict__ A,
                                              const uint16_t* __restrict__ Bt,
                                              const float* __restrict__ bias,
                                              uint16_t* __restrict__ C, int M, int N, int K) {
  __shared__ uint16_t As[2][128 * 32];   // [k-half][row*32 + k]  (64B rows)
  __shared__ uint16_t Bs[2][128 * 32];
  const int tid = threadIdx.x, lane = tid & 63, wave = tid >> 6;
  // chunked-XCD swizzle: XCD (d&7) owns a contiguous wg range => the N/128
  // blocks sharing one A-panel are co-resident on one XCD's L2.
  int d = blockIdx.x;
  const int nwg = gridDim.x;
  if ((nwg & 7) == 0) d = (d & 7) * (nwg >> 3) + (d >> 3);
  const int ntl = N >> 7;                       // N-tiles (n-major: fastest)
  const int m0 = (d / ntl) * 128, n0 = (d % ntl) * 128;
  const int wm = wave & 1, wn = wave >> 1;
  const int frow = lane & 15, kb = lane >> 4;
  const int lr = lane >> 2, kc = lane & 3;
  v4f acc[4][4] = {};

  for (int k0 = 0; k0 < K; k0 += 64) {
    __syncthreads();
    #pragma unroll
    for (int t = 0; t < 2; t++)
      #pragma unroll
      for (int i = 0; i < 2; i++) {
        const int r = (wave * 2 + i) * 16 + lr;
        const uint16_t* ga = A + (size_t)(m0 + r) * K + k0 + t * 32 + kc * 8;
        const uint16_t* gb = Bt + (size_t)(n0 + r) * K + k0 + t * 32 + kc * 8;
        __builtin_amdgcn_global_load_lds(
            (const __attribute__((address_space(1))) void*)ga,
            (__attribute__((address_space(3))) void*)(&As[t][0] + (wave * 2 + i) * 512 + lane * 8), 16, 0, 0);
        __builtin_amdgcn_global_load_lds(
            (const __attribute__((address_space(1))) void*)gb,
            (__attribute__((address_space(3))) void*)(&Bs[t][0] + (wave * 2 + i) * 512 + lane * 8), 16, 0, 0);
      }
    __syncthreads();

    #pragma unroll
    for (int t = 0; t < 2; t++) {
      v8s af[4], bf[4];
      #pragma unroll
      for (int i = 0; i < 4; i++)
        af[i] = *(const v8s*)(&As[t][0] + (wm * 64 + i * 16 + frow) * 32 + kb * 8);
      #pragma unroll
      for (int j = 0; j < 4; j++)
        bf[j] = *(const v8s*)(&Bs[t][0] + (wn * 64 + j * 16 + frow) * 32 + kb * 8);
      #pragma unroll
      for (int i = 0; i < 4; i++)
        #pragma unroll
        for (int j = 0; j < 4; j++)
          acc[i][j] = __builtin_amdgcn_mfma_f32_16x16x32_bf16(af[i], bf[j], acc[i][j], 0, 0, 0);
    }
  }

  // epilogue: C/D layout col=lane&15, row=(lane>>4)*4+reg  [m89-verified]
  const int crow = (lane >> 4) * 4, ccol = lane & 15;
  #pragma unroll
  for (int j = 0; j < 4; j++) {
    const int n = n0 + wn * 64 + j * 16 + ccol;
    const float bv = bias[n];
    #pragma unroll
    for (int i = 0; i < 4; i++) {
      const int mb = m0 + wm * 64 + i * 16 + crow;
      #pragma unroll
      for (int r2 = 0; r2 < 4; r2++)
        C[(size_t)(mb + r2) * N + n] = (uint16_t)f2bf_bits(acc[i][j][r2] + bv);
    }
  }
}

// ---------------- k_softmax_gather: row lse + gather (linear domain) ----------------
__global__ void k_softmax_gather(const uint16_t* __restrict__ logits, const int* __restrict__ target,
                                 const int* __restrict__ tlen, float* __restrict__ pext,
                                 int T, int V, int L) {
  const int row = blockIdx.x * 4 + (threadIdx.x >> 6);   // one wave per row
  const int lane = threadIdx.x & 63;
  const uint16_t* lrow = logits + (size_t)row * V;

  float xs[16];
  int cnt = 0;
  float mx = -INFINITY;
  for (int base = 0; base < V; base += 256) {
    const int idx = base + lane * 4;
    uint2 u = *(const uint2*)(lrow + idx);
    float4 v;
    v.x = bf2f(u.x & 0xFFFFu); v.y = bf2f(u.x >> 16);
    v.z = bf2f(u.y & 0xFFFFu); v.w = bf2f(u.y >> 16);
    xs[cnt] = v.x; xs[cnt + 1] = v.y; xs[cnt + 2] = v.z; xs[cnt + 3] = v.w; cnt += 4;
    mx = fmaxf(mx, fmaxf(fmaxf(v.x, v.y), fmaxf(v.z, v.w)));
  }
  #pragma unroll
  for (int off = 32; off; off >>= 1) mx = fmaxf(mx, __shfl_xor(mx, off, 64));
  float sum = 0.f;
  #pragma unroll
  for (int q = 0; q < 16; q++) { if (q < cnt) sum += exp2f((xs[q] - mx) * L2E); }
  #pragma unroll
  for (int off = 32; off; off >>= 1) sum += __shfl_xor(sum, off, 64);
  const float lse2 = mx * L2E + log2f(sum);

  const int bidx = row / T;
  const int Lb = tlen[bidx];
  const int S = 2 * Lb + 1;
  float* prow = pext + (size_t)row * PROW;
  #pragma unroll
  for (int it = 0; it < PROW / 64; it++) {
    const int s = lane + it * 64;
    float p = 0.f;
    if (s < S) {
      const int lbl = (s & 1) ? target[bidx * L + ((s - 1) >> 1)] : 0;
      p = exp2f(bf2f(lrow[lbl]) * L2E - lse2);
    }
    prow[s] = p;
  }
}

// ---------------- k_ctc: scaled linear-domain CTC forward, 1 wave per batch ----------------
__device__ __forceinline__ float wave_shr1(float x) {   // lane l <- lane l-1, lane0 <- 0
  return __int_as_float(__builtin_amdgcn_update_dpp(0, __float_as_int(x), 0x138, 0xf, 0xf, true));
}
__device__ __forceinline__ float wave_max_nonneg(float x) {
  x = fmaxf(x, __int_as_float(__builtin_amdgcn_update_dpp(0, __float_as_int(x), 0x111, 0xf, 0xf, true)));
  x = fmaxf(x, __int_as_float(__builtin_amdgcn_update_dpp(0, __float_as_int(x), 0x112, 0xf, 0xf, true)));
  x = fmaxf(x, __int_as_float(__builtin_amdgcn_update_dpp(0, __float_as_int(x), 0x114, 0xf, 0xf, true)));
  x = fmaxf(x, __int_as_float(__builtin_amdgcn_update_dpp(0, __float_as_int(x), 0x118, 0xf, 0xf, true)));
  x = fmaxf(x, __int_as_float(__builtin_amdgcn_update_dpp(0, __float_as_int(x), 0x142, 0xf, 0xf, true)));
  x = fmaxf(x, __int_as_float(__builtin_amdgcn_update_dpp(0, __float_as_int(x), 0x143, 0xf, 0xf, true)));
  return __int_as_float(__builtin_amdgcn_readlane(__float_as_int(x), 63));
}

// 8-row chunk load: pure float4 loads, 8 VMEM ops total (the minimum for 8 KiB).
__device__ __forceinline__ void load8(float4* __restrict__ p,
                                      const float* __restrict__ pb, int t0, int lane) {
  #pragma unroll
  for (int k = 0; k < 8; k++)
    p[k] = *(const float4*)(pb + (size_t)(t0 + k) * PROW + (lane << 2));
}

__global__ __launch_bounds__(64, 1) void k_ctc(const float* __restrict__ pext,
                                               const int* __restrict__ target,
                                               const int* __restrict__ ilen,
                                               const int* __restrict__ tlen,
                                               float* __restrict__ out, int T, int L) {
  const int b = blockIdx.x;
  const int lane = threadIdx.x;          // 64 threads = 1 wave
  const int B = gridDim.x;
  const int Tb = ilen[b];
  const int Lb = tlen[b];
  const int S = 2 * Lb + 1;
  const int* tg = target + b * L;

  const int s1 = 4 * lane + 1, s3 = 4 * lane + 3;
  float sk1 = 0.f, sk3 = 0.f;
  if (s1 >= 3 && s1 < S) sk1 = (tg[(s1 - 1) >> 1] != tg[(s1 - 3) >> 1]) ? 1.f : 0.f;
  if (s3 >= 3 && s3 < S) sk3 = (tg[(s3 - 1) >> 1] != tg[(s3 - 3) >> 1]) ? 1.f : 0.f;

  const float* pb = pext + (size_t)b * T * PROW;
  const float4 p0 = *(const float4*)(pb + (lane << 2));
  float a0 = (lane == 0) ? p0.x : 0.f;
  float a1 = (lane == 0) ? p0.y : 0.f;
  float a2 = 0.f, a3 = 0.f, a4 = 0.f;
  float log2C = 0.f;

  // State 256 is even -> blank -> its prob equals prow[0] (lane 0's P.x):
  // recover it with readlane instead of a separate load stream.
  #define CTC_STEP(PP) {                                                \
    const float pm3 = wave_shr1(a3);                                    \
    const float a255 = __int_as_float(__builtin_amdgcn_readlane(__float_as_int(a3), 63)); \
    const float p4v = __int_as_float(__builtin_amdgcn_readlane(__float_as_int((PP).x), 0)); \
    const float n0v = (a0 + pm3) * (PP).x;                              \
    const float n1v = (a1 + a0 + sk1 * pm3) * (PP).y;                   \
    const float n2v = (a2 + a1) * (PP).z;                               \
    const float n3v = (a3 + a2 + sk3 * a1) * (PP).w;                    \
    const float n4v = (a4 + a255) * p4v;                                \
    a0 = n0v; a1 = n1v; a2 = n2v; a3 = n3v; a4 = n4v; }

  #define RENORM {                                                      \
    float m = fmaxf(fmaxf(fmaxf(a0, a1), fmaxf(a2, a3)), a4);           \
    m = wave_max_nonneg(m);                                             \
    const int e = (int)((__float_as_uint(m) >> 23) & 255u) - 127;       \
    const float scale = __uint_as_float((uint32_t)(127 - e) << 23);     \
    a0 *= scale; a1 *= scale; a2 *= scale; a3 *= scale; a4 *= scale;    \
    log2C += (float)e; }

  // 4-stage software pipeline, 8-row chunks, prefetch distance = 3 chunks.
  // sched_barrier(0) after each load block pins the loads ABOVE the compute:
  // without it the compiler sinks each load to its first use, serializing on
  // memory latency (R1 evidence).
  float4 Pa[8], Pb_[8], Pc[8], Pd[8];
  int t0 = 1;
  bool done = false;
  load8(Pa, pb, t0, lane);
  load8(Pb_, pb, t0 + 8, lane);
  load8(Pc, pb, t0 + 16, lane);
  __builtin_amdgcn_sched_barrier(0);

  #define PHASE(LP, CP) {                                               \
    if (t0 + 8 <= Tb) {                                                 \
      load8(LP, pb, t0 + 24, lane);                                     \
      __builtin_amdgcn_sched_barrier(0);                                \
      _Pragma("unroll")                                                 \
      for (int k = 0; k < 8; k++) CTC_STEP(CP[k]);                      \
      RENORM; t0 += 8;                                                  \
    } else {                                                            \
      _Pragma("unroll")                                                 \
      for (int k = 0; k < 8; k++) { if (t0 + k < Tb) CTC_STEP(CP[k]); } \
      RENORM; done = true;                                              \
    } }

  while (!done) {
    PHASE(Pd, Pa); if (done) break;
    PHASE(Pa, Pb_); if (done) break;
    PHASE(Pb_, Pc); if (done) break;
    PHASE(Pc, Pd);
  }

  __shared__ float abuf[257];
  abuf[4 * lane + 0] = a0; abuf[4 * lane + 1] = a1;
  abuf[4 * lane + 2] = a2; abuf[4 * lane + 3] = a3;
  if (lane == 63) abuf[256] = a4;
  __syncthreads();
  if (lane == 0) {
    const float ssum = abuf[2 * Lb - 1] + abuf[2 * Lb];
    const float ll = (log2f(ssum) + log2C) * LN2;
    float nll = -ll;
    if (!(nll < 1e29f)) nll = 0.f;                 // zero_infinity (also catches inf/nan)
    atomicAdd(out, nll / ((float)(Lb > 0 ? Lb : 1) * (float)B));
  }
}

// ---------------------------------------------------------------------------
extern "C" void kernel_launch(void* const* d_in, const int* in_sizes, int n_in,
                              void* d_out, int out_size, void* d_ws, size_t ws_size,
                              hipStream_t stream) {
  const float* x      = (const float*)d_in[0];
  const float* W      = (const float*)d_in[1];
  const float* bias   = (const float*)d_in[2];
  const int*  target  = (const int*)d_in[3];
  const int*  ilen    = (const int*)d_in[4];
  const int*  tlen    = (const int*)d_in[5];

  const int B = in_sizes[4];
  const int V = in_sizes[2];
  const int D = in_sizes[1] / V;
  const int T = in_sizes[0] / (B * D);
  const int L = in_sizes[3] / B;
  const int M = B * T;

  char* ws = (char*)d_ws;
  const size_t xb_bytes = (size_t)M * D * 2;
  const size_t wt_bytes = (size_t)V * D * 2;
  uint16_t* xb = (uint16_t*)ws;
  uint16_t* Wt = (uint16_t*)(ws + xb_bytes);
  uint16_t* logits = (uint16_t*)(ws + xb_bytes + wt_bytes);
  const size_t log_bytes = (size_t)M * V * 2;

  const size_t pext_bytes = (size_t)(M + PEXT_PAD_ROWS) * PROW * 4;
  float* pext;
  if (pext_bytes <= xb_bytes + wt_bytes) {
    pext = (float*)ws;                 // overlay dead xb/Wt region after GEMM
  } else {
    pext = (float*)(ws + xb_bytes + wt_bytes + log_bytes);
  }

  const long long nx = (long long)M * D;
  const int nconv = (int)((nx / 8 + 255) / 256);
  const int ntrans = (V / 32) * (D / 32);
  k_prep<<<nconv + ntrans, 256, 0, stream>>>(x, xb, nx, W, Wt, D, V, (float*)d_out, nconv);
  k_gemm<<<(M / 128) * (V / 128), 256, 0, stream>>>(xb, Wt, bias, logits, M, V, D);
  k_softmax_gather<<<M / 4, 256, 0, stream>>>(logits, target, tlen, pext, T, V, L);
  k_ctc<<<B, 64, 0, stream>>>(pext, target, ilen, tlen, (float*)d_out, T, L);
}